// Round 8
// baseline (124.846 us; speedup 1.0000x reference)
//
#include <hip/hip_runtime.h>
#include <stdint.h>
#include <math.h>

// Kuramoto dynamics, B=65536 x N=60, 10 steps.
// R11: 8-accumulator MFMA schedule on R10's exchange-free 32x32x16 structure.
//   R10 post-mortem: passed at 53us but stall-dominated (issue work ~38k
//   cyc/SIMD vs wall 128k). The 32x32 restructure cut accumulators 8 -> 4;
//   same-acc reuse distance 4 x 8cyc = 32 cyc < dependent MFMA latency ->
//   per-MFMA bubbles. (R4's 16x16 structure had distance 8 and no such gap.)
//   Fix: process kb in PAIRS; 24 MFMAs per pair rotating 8 accumulators
//   (even-kb partials + odd-kb partials) -> distance 8 x 8 = 64 cyc.
//   Merge S = Se + So in the update (1 add/elem). Numerics: per-acc product
//   order unchanged (kb0: H.BH,L.BH,H.BL then kb2... / kb1 then kb3); the
//   single final reassociation add perturbs coupling ~1e-8 -> theta ~1e-11
//   per step, 4-5 orders below the ~1e-7 wrap-flip threshold.
// Carried from R10:
//   - sigma-gathered A columns (A slot(h,j) = Ke[m][16kb+(j&3)+8(j>>2)+4h])
//     so B packing is the IDENTITY on C/D state elems -- no cross-lane ops.
//   - update: 4 separately-rounded f32 ops (#pragma clang fp contract(off))
//   - wrap: branch-free, boundary-exact (|x| >= f32(pi) predicate)
//   - HW __sincosf only on paths attenuated by eff_dt*scale ~1e-3

#define B_TOTAL 65536
#define NOSC 60
#define STEPS 10

using short8v  = __attribute__((ext_vector_type(8))) short;
using floatx16 = __attribute__((ext_vector_type(16))) float;
using bf16x8   = __attribute__((ext_vector_type(8))) __bf16;

#if __has_builtin(__builtin_amdgcn_perm)
__device__ __forceinline__ unsigned int perm_b32(unsigned int s0, unsigned int s1, unsigned int sel) {
    return __builtin_amdgcn_perm(s0, s1, sel);
}
#else
__device__ __forceinline__ unsigned int perm_b32(unsigned int s0, unsigned int s1, unsigned int sel) {
    unsigned long long pool = ((unsigned long long)s0 << 32) | s1;
    unsigned int r = 0;
#pragma unroll
    for (int b = 0; b < 4; ++b) {
        unsigned int s = (sel >> (8 * b)) & 0xff;
        r |= ((unsigned int)((pool >> (8 * s)) & 0xff)) << (8 * b);
    }
    return r;
}
#endif

__device__ __forceinline__ unsigned int fbits(float x)        { return __builtin_bit_cast(unsigned int, x); }
__device__ __forceinline__ float        bitsf(unsigned int u) { return __builtin_bit_cast(float, u); }

// 32x32x16 bf16 MFMA. Builtin if present (v8bf16 operands), else inline asm.
__device__ __forceinline__ floatx16 mfma32(short8v a, short8v b, floatx16 c) {
#if __has_builtin(__builtin_amdgcn_mfma_f32_32x32x16_bf16)
    return __builtin_amdgcn_mfma_f32_32x32x16_bf16(
        __builtin_bit_cast(bf16x8, a), __builtin_bit_cast(bf16x8, b), c, 0, 0, 0);
#else
    asm("v_mfma_f32_32x32x16_bf16 %0, %1, %2, %0" : "+v"(c) : "v"(a), "v"(b));
    return c;
#endif
}

// pack bf16-hi(a) into low half, bf16-hi(b) into high half of one b32
__device__ __forceinline__ unsigned int pack_hi_pair(float a, float b) {
    return perm_b32(fbits(b), fbits(a), 0x07060302u);
}

union BU { unsigned u[4]; short8v v; };

// pack one kb's four B operand vectors from state elems (obp, r0..r0+7)
__device__ __forceinline__ void pack_B(const float (&sn)[2][16], const float (&cn)[2][16],
                                       int obp, int r0,
                                       BU &Bsh, BU &Bsl, BU &Bch, BU &Bcl)
{
    float sl_[8], cl_[8];
#pragma unroll
    for (int s = 0; s < 8; ++s) {
        const unsigned us = fbits(sn[obp][r0+s]);
        sl_[s] = sn[obp][r0+s] - bitsf(us & 0xffff0000u);
        const unsigned uc = fbits(cn[obp][r0+s]);
        cl_[s] = cn[obp][r0+s] - bitsf(uc & 0xffff0000u);
    }
#pragma unroll
    for (int p = 0; p < 4; ++p) {
        Bsh.u[p] = pack_hi_pair(sn[obp][r0+2*p], sn[obp][r0+2*p+1]);
        Bsl.u[p] = pack_hi_pair(sl_[2*p], sl_[2*p+1]);
        Bch.u[p] = pack_hi_pair(cn[obp][r0+2*p], cn[obp][r0+2*p+1]);
        Bcl.u[p] = pack_hi_pair(cl_[2*p], cl_[2*p+1]);
    }
}

__global__ __launch_bounds__(64)
void kuramoto_kernel(const float* __restrict__ theta_in,
                     const float* __restrict__ Kmat,
                     const float* __restrict__ omega,
                     const float* __restrict__ p_kglobal,
                     const float* __restrict__ p_cmod,
                     const float* __restrict__ p_gate,
                     const float* __restrict__ p_slow,
                     const float* __restrict__ p_dsneg,
                     const float* __restrict__ p_relax,
                     float* __restrict__ theta_out,
                     float* __restrict__ coh_out)
{
    const int lane = threadIdx.x & 63;
    const int c    = lane & 31;   // batch within tile
    const int h    = lane >> 5;   // lane half

    const float kglobal = p_kglobal[0];
    const float cmod    = p_cmod[0];
    const float gate    = p_gate[0];
    const float slow    = p_slow[0];
    const float dsneg   = p_dsneg[0];
    const float relax   = p_relax[0];

    float eff_dt, scale;
    {
#pragma clang fp contract(off)
        const float a     = slow * relax;
        const float b     = 1.0f + a;
        const float crit  = 1.0f / b;
        eff_dt            = 0.1f * crit;
        const float boost = 1.0f + gate * dsneg;
        scale             = (kglobal * boost) / 60.0f;
    }

    const int batch0 = blockIdx.x * 32;
    const int brow   = (batch0 + c) * NOSC;

    // ---- A operand (loop-invariant): Ke = K*cmod, hi/lo trunc split, with
    // sigma-gathered k columns: A slot (h,j) = Ke[m][16*kb + (j&3) + 8*(j>>2) + 4*h]
    // matching the natural (identity) B packing of C/D state elems.
    short8v AH[2][4], AL[2][4];
#pragma unroll
    for (int ob = 0; ob < 2; ++ob) {
        const int m = 32 * ob + c;
        const bool okm = (m < NOSC);          // zero rows >= 60 -> acc rows 60..63 = 0
#pragma unroll
        for (int kb = 0; kb < 4; ++kb) {
            const int base = 16 * kb + 4 * h;
            float kv[8];
            if (okm && (base + 11) < NOSC) {
                const float4 a = *(const float4*)(Kmat + m * NOSC + base);
                const float4 b = *(const float4*)(Kmat + m * NOSC + base + 8);
                kv[0]=a.x; kv[1]=a.y; kv[2]=a.z; kv[3]=a.w;
                kv[4]=b.x; kv[5]=b.y; kv[6]=b.z; kv[7]=b.w;
            } else {
#pragma unroll
                for (int j = 0; j < 8; ++j) {
                    const int col = base + (j & 3) + 8 * (j >> 2);
                    kv[j] = (okm && col < NOSC) ? Kmat[m * NOSC + col] : 0.0f;
                }
            }
            short8v hh, ll;
#pragma unroll
            for (int j = 0; j < 8; ++j) {
                const float v = kv[j] * cmod;
                const unsigned int hb = fbits(v) & 0xffff0000u;
                const float rlo = v - bitsf(hb);
                hh[j] = (short)(hb >> 16);
                ll[j] = (short)(fbits(rlo) >> 16);
            }
            AH[ob][kb] = hh;
            AL[ob][kb] = ll;
        }
    }

    // ---- state in 32x32 C/D layout: elem (ob, reg) holds
    //   osc o = 32*ob + (reg&3) + 8*(reg>>2) + 4*h, batch = batch0 + c
    float th[2][16], sn[2][16], cn[2][16], omg[2][16];
#pragma unroll
    for (int ob = 0; ob < 2; ++ob) {
#pragma unroll
        for (int g = 0; g < 4; ++g) {
            const int o0 = 32 * ob + 8 * g + 4 * h;
            const int rb = 4 * g;
            if (o0 + 3 < NOSC) {               // pad only (ob=1,g=3,h=1): osc 60-63
                const float4 tv = *(const float4*)(theta_in + brow + o0);
                const float4 ov = *(const float4*)(omega + o0);
                th[ob][rb+0] = tv.x; th[ob][rb+1] = tv.y; th[ob][rb+2] = tv.z; th[ob][rb+3] = tv.w;
                omg[ob][rb+0] = ov.x; omg[ob][rb+1] = ov.y; omg[ob][rb+2] = ov.z; omg[ob][rb+3] = ov.w;
            } else {
#pragma unroll
                for (int m = 0; m < 4; ++m) { th[ob][rb+m] = 0.0f; omg[ob][rb+m] = 0.0f; }
            }
#pragma unroll
            for (int m = 0; m < 4; ++m)
                __sincosf(th[ob][rb+m], &sn[ob][rb+m], &cn[ob][rb+m]);
        }
    }

    // wrap constants (boundary-exact, see R3 notes)
    const float PI_F = 3.14159274101257324f;
    const float C_HI = 6.28318548202514648f;    // f32(2pi)
    const float C_LO = -1.7484556e-7f;          // 2pi - C_HI (f64-accurate)

#pragma unroll 1
    for (int t = 0; t < STEPS; ++t) {
        // 8 accumulators: even-kb partials (e) and odd-kb partials (o).
        floatx16 aS0e, aS1e, aC0e, aC1e, aS0o, aS1o, aC0o, aC1o;
        const floatx16 Z = (floatx16)0.0f;

#pragma unroll
        for (int kp = 0; kp < 2; ++kp) {
            const int ke = 2 * kp;       // even kb of the pair
            const int ko = 2 * kp + 1;   // odd kb
            // B source rows: kb -> (obp = kb>>1, r0 = (kb&1)*8); identity pack.
            BU BshE, BslE, BchE, BclE, BshO, BslO, BchO, BclO;
            pack_B(sn, cn, ke >> 1, (ke & 1) * 8, BshE, BslE, BchE, BclE);
            pack_B(sn, cn, ko >> 1, (ko & 1) * 8, BshO, BslO, BchO, BclO);

            // 24 MFMAs rotating 8 accs: same-acc reuse distance 8 (= 64 issue cyc).
            // Per-acc product order: H.BH, L.BH, H.BL within its kb -- unchanged.
            aS0e = mfma32(AH[0][ke], BshE.v, kp ? aS0e : Z);
            aS1e = mfma32(AH[1][ke], BshE.v, kp ? aS1e : Z);
            aC0e = mfma32(AH[0][ke], BchE.v, kp ? aC0e : Z);
            aC1e = mfma32(AH[1][ke], BchE.v, kp ? aC1e : Z);
            aS0o = mfma32(AH[0][ko], BshO.v, kp ? aS0o : Z);
            aS1o = mfma32(AH[1][ko], BshO.v, kp ? aS1o : Z);
            aC0o = mfma32(AH[0][ko], BchO.v, kp ? aC0o : Z);
            aC1o = mfma32(AH[1][ko], BchO.v, kp ? aC1o : Z);

            aS0e = mfma32(AL[0][ke], BshE.v, aS0e);
            aS1e = mfma32(AL[1][ke], BshE.v, aS1e);
            aC0e = mfma32(AL[0][ke], BchE.v, aC0e);
            aC1e = mfma32(AL[1][ke], BchE.v, aC1e);
            aS0o = mfma32(AL[0][ko], BshO.v, aS0o);
            aS1o = mfma32(AL[1][ko], BshO.v, aS1o);
            aC0o = mfma32(AL[0][ko], BchO.v, aC0o);
            aC1o = mfma32(AL[1][ko], BchO.v, aC1o);

            aS0e = mfma32(AH[0][ke], BslE.v, aS0e);
            aS1e = mfma32(AH[1][ke], BslE.v, aS1e);
            aC0e = mfma32(AH[0][ke], BclE.v, aC0e);
            aC1e = mfma32(AH[1][ke], BclE.v, aC1e);
            aS0o = mfma32(AH[0][ko], BslO.v, aS0o);
            aS1o = mfma32(AH[1][ko], BslO.v, aS1o);
            aC0o = mfma32(AH[0][ko], BclO.v, aC0o);
            aC1o = mfma32(AH[1][ko], BclO.v, aC1o);
        }

        // ---- update: merge partials (S = Se + So), then ref-exact association
        // + boundary-exact wrap. (Merge add reassociation ~1e-8 on coupling ->
        // ~1e-11 on theta per step: negligible vs the ~1e-7 flip threshold.)
#pragma unroll
        for (int ob = 0; ob < 2; ++ob) {
            const floatx16 &aSe = ob ? aS1e : aS0e;
            const floatx16 &aSo = ob ? aS1o : aS0o;
            const floatx16 &aCe = ob ? aC1e : aC0e;
            const floatx16 &aCo = ob ? aC1o : aC0o;
#pragma unroll
            for (int r = 0; r < 16; ++r) {
                const float S = aSe[r] + aSo[r];
                const float C = aCe[r] + aCo[r];
                const float coup = cn[ob][r] * S - sn[ob][r] * C;  // approx path: fma ok
                float nth;
                {
#pragma clang fp contract(off)
                    const float t1 = scale * coup;       // np: scale*coupling_sum
                    const float t2 = omg[ob][r] + t1;    // np: omega + ...
                    const float t3 = eff_dt * t2;        // np: eff_dt * (...)
                    nth = th[ob][r] + t3;                // np: th + ...
                }
                float n = 0.0f;
                n = (nth >=  PI_F) ?  1.0f : n;
                n = (nth <= -PI_F) ? -1.0f : n;
                float y = fmaf(n, -C_HI, nth);
                y = fmaf(n, -C_LO, y);
                th[ob][r] = y;
                __sincosf(y, &sn[ob][r], &cn[ob][r]);
            }
        }
    }

    // ---- epilogue: store wrapped theta (float4 per (ob,g), pad chunk skipped)
#pragma unroll
    for (int ob = 0; ob < 2; ++ob) {
#pragma unroll
        for (int g = 0; g < 4; ++g) {
            const int o0 = 32 * ob + 8 * g + 4 * h;
            const int rb = 4 * g;
            if (o0 + 3 < NOSC) {
                float4 tv;
                tv.x = th[ob][rb+0]; tv.y = th[ob][rb+1];
                tv.z = th[ob][rb+2]; tv.w = th[ob][rb+3];
                *(float4*)(theta_out + brow + o0) = tv;
            }
        }
    }

    // ---- coherence: batch = batch0 + c split across lane halves.
    // Pad elems (ob=1, regs 12-15, h=1) hold exactly (sn,cn)=(0,1) forever:
    // sum all 32 then subtract the 4 pad cosines at h==1.
    float pc = 0.0f, ps = 0.0f;
#pragma unroll
    for (int ob = 0; ob < 2; ++ob)
#pragma unroll
        for (int r = 0; r < 16; ++r) { pc += cn[ob][r]; ps += sn[ob][r]; }
    pc -= h ? 4.0f : 0.0f;
    pc += __shfl_xor(pc, 32);
    ps += __shfl_xor(ps, 32);
    if (h == 0) {
        const float cm = pc / 60.0f;
        const float sm = ps / 60.0f;
        coh_out[batch0 + c] = sqrtf(cm * cm + sm * sm);
    }
}

extern "C" void kernel_launch(void* const* d_in, const int* in_sizes, int n_in,
                              void* d_out, int out_size, void* d_ws, size_t ws_size,
                              hipStream_t stream) {
    const float* theta = (const float*)d_in[0];
    const float* Kmat  = (const float*)d_in[1];
    const float* omg   = (const float*)d_in[2];
    const float* kg    = (const float*)d_in[3];
    const float* cmod  = (const float*)d_in[4];
    const float* gate  = (const float*)d_in[5];
    const float* slow  = (const float*)d_in[6];
    const float* dsn   = (const float*)d_in[7];
    const float* relax = (const float*)d_in[8];
    float* out = (float*)d_out;

    kuramoto_kernel<<<dim3(B_TOTAL / 32), dim3(64), 0, stream>>>(
        theta, Kmat, omg, kg, cmod, gate, slow, dsn, relax,
        out, out + (size_t)B_TOTAL * NOSC);
}

// Round 9
// 121.015 us; speedup vs baseline: 1.0317x; 1.0317x over previous
//
#include <hip/hip_runtime.h>
#include <stdint.h>
#include <math.h>

// Kuramoto dynamics, B=65536 x N=60, 10 steps.
// R12: R10 (best, 53us) + guaranteed-NATIVE sincos via inline asm.
//   R11 (8-acc) regressed -> reverted; MFMA dep distance is not the stall.
//   Whole-chip arithmetic: wall ~128k cyc/CU at VALUBusy ~50% -> ~50 VALU
//   instr per element-update, but source-level update is only ~21 ops/elem.
//   The ~30-instr gap matches an ocml-style __sincosf expansion (range
//   reduction + Cody-Waite + quadrant fixups) instead of raw v_sin/v_cos.
//   Fix: fast_sincos = 1 shared v_mul (x * 1/2pi, inline const) + v_sin_f32
//   + v_cos_f32 (D = sin/cos(S0*2pi); |rev| < 0.6 << HW range, no fract).
// Numerics: theta path untouched (bitwise identical to R10). Native sin/cos
//   error (~1e-6 abs worst) enters only attenuated paths:
//   - coupling x eff_dt*scale ~2e-3 -> theta ~1e-9/step << 1e-7 flip cliff
//   - coherence: threshold 6.28e-2, headroom 4x.
// Carried from R10:
//   - exchange-free 32x32x16 MFMA: sigma-gathered A columns
//     (A slot(h,j) = Ke[m][16kb+(j&3)+8(j>>2)+4h]) so B packing is the
//     IDENTITY on C/D state elems; zero cross-lane ops in the loop.
//   - 3-product split: KH.sH + KL.sH + KH.sL, kb order 0..3
//   - update: 4 separately-rounded f32 ops (#pragma clang fp contract(off))
//   - wrap: branch-free, boundary-exact (|x| >= f32(pi) predicate)

#define B_TOTAL 65536
#define NOSC 60
#define STEPS 10

using short8v  = __attribute__((ext_vector_type(8))) short;
using floatx16 = __attribute__((ext_vector_type(16))) float;
using bf16x8   = __attribute__((ext_vector_type(8))) __bf16;

#if __has_builtin(__builtin_amdgcn_perm)
__device__ __forceinline__ unsigned int perm_b32(unsigned int s0, unsigned int s1, unsigned int sel) {
    return __builtin_amdgcn_perm(s0, s1, sel);
}
#else
__device__ __forceinline__ unsigned int perm_b32(unsigned int s0, unsigned int s1, unsigned int sel) {
    unsigned long long pool = ((unsigned long long)s0 << 32) | s1;
    unsigned int r = 0;
#pragma unroll
    for (int b = 0; b < 4; ++b) {
        unsigned int s = (sel >> (8 * b)) & 0xff;
        r |= ((unsigned int)((pool >> (8 * s)) & 0xff)) << (8 * b);
    }
    return r;
}
#endif

__device__ __forceinline__ unsigned int fbits(float x)        { return __builtin_bit_cast(unsigned int, x); }
__device__ __forceinline__ float        bitsf(unsigned int u) { return __builtin_bit_cast(float, u); }

// native sincos: v_sin_f32/v_cos_f32 compute sin/cos(S0 * 2pi).
// |x| <= pi + ~0.5 -> |rev| < 0.6, inside HW range (no v_fract needed).
__device__ __forceinline__ void fast_sincos(float x, float* s, float* c) {
    const float r = x * 0.15915494309189535f;   // 1/(2pi)
    float sv, cv;
    asm("v_sin_f32 %0, %1" : "=v"(sv) : "v"(r));
    asm("v_cos_f32 %0, %1" : "=v"(cv) : "v"(r));
    *s = sv;
    *c = cv;
}

// 32x32x16 bf16 MFMA. Builtin if present (v8bf16 operands), else inline asm.
__device__ __forceinline__ floatx16 mfma32(short8v a, short8v b, floatx16 c) {
#if __has_builtin(__builtin_amdgcn_mfma_f32_32x32x16_bf16)
    return __builtin_amdgcn_mfma_f32_32x32x16_bf16(
        __builtin_bit_cast(bf16x8, a), __builtin_bit_cast(bf16x8, b), c, 0, 0, 0);
#else
    asm("v_mfma_f32_32x32x16_bf16 %0, %1, %2, %0" : "+v"(c) : "v"(a), "v"(b));
    return c;
#endif
}

// pack bf16-hi(a) into low half, bf16-hi(b) into high half of one b32
__device__ __forceinline__ unsigned int pack_hi_pair(float a, float b) {
    return perm_b32(fbits(b), fbits(a), 0x07060302u);
}

__global__ __launch_bounds__(64)
void kuramoto_kernel(const float* __restrict__ theta_in,
                     const float* __restrict__ Kmat,
                     const float* __restrict__ omega,
                     const float* __restrict__ p_kglobal,
                     const float* __restrict__ p_cmod,
                     const float* __restrict__ p_gate,
                     const float* __restrict__ p_slow,
                     const float* __restrict__ p_dsneg,
                     const float* __restrict__ p_relax,
                     float* __restrict__ theta_out,
                     float* __restrict__ coh_out)
{
    const int lane = threadIdx.x & 63;
    const int c    = lane & 31;   // batch within tile
    const int h    = lane >> 5;   // lane half

    const float kglobal = p_kglobal[0];
    const float cmod    = p_cmod[0];
    const float gate    = p_gate[0];
    const float slow    = p_slow[0];
    const float dsneg   = p_dsneg[0];
    const float relax   = p_relax[0];

    float eff_dt, scale;
    {
#pragma clang fp contract(off)
        const float a     = slow * relax;
        const float b     = 1.0f + a;
        const float crit  = 1.0f / b;
        eff_dt            = 0.1f * crit;
        const float boost = 1.0f + gate * dsneg;
        scale             = (kglobal * boost) / 60.0f;
    }

    const int batch0 = blockIdx.x * 32;
    const int brow   = (batch0 + c) * NOSC;

    // ---- A operand (loop-invariant): Ke = K*cmod, hi/lo trunc split, with
    // sigma-gathered k columns: A slot (h,j) = Ke[m][16*kb + (j&3) + 8*(j>>2) + 4*h]
    // matching the natural (identity) B packing of C/D state elems.
    short8v AH[2][4], AL[2][4];
#pragma unroll
    for (int ob = 0; ob < 2; ++ob) {
        const int m = 32 * ob + c;
        const bool okm = (m < NOSC);          // zero rows >= 60 -> acc rows 60..63 = 0
#pragma unroll
        for (int kb = 0; kb < 4; ++kb) {
            const int base = 16 * kb + 4 * h;
            float kv[8];
            if (okm && (base + 11) < NOSC) {
                const float4 a = *(const float4*)(Kmat + m * NOSC + base);
                const float4 b = *(const float4*)(Kmat + m * NOSC + base + 8);
                kv[0]=a.x; kv[1]=a.y; kv[2]=a.z; kv[3]=a.w;
                kv[4]=b.x; kv[5]=b.y; kv[6]=b.z; kv[7]=b.w;
            } else {
#pragma unroll
                for (int j = 0; j < 8; ++j) {
                    const int col = base + (j & 3) + 8 * (j >> 2);
                    kv[j] = (okm && col < NOSC) ? Kmat[m * NOSC + col] : 0.0f;
                }
            }
            short8v hh, ll;
#pragma unroll
            for (int j = 0; j < 8; ++j) {
                const float v = kv[j] * cmod;
                const unsigned int hb = fbits(v) & 0xffff0000u;
                const float rlo = v - bitsf(hb);
                hh[j] = (short)(hb >> 16);
                ll[j] = (short)(fbits(rlo) >> 16);
            }
            AH[ob][kb] = hh;
            AL[ob][kb] = ll;
        }
    }

    // ---- state in 32x32 C/D layout: elem (ob, reg) holds
    //   osc o = 32*ob + (reg&3) + 8*(reg>>2) + 4*h, batch = batch0 + c
    float th[2][16], sn[2][16], cn[2][16], omg[2][16];
#pragma unroll
    for (int ob = 0; ob < 2; ++ob) {
#pragma unroll
        for (int g = 0; g < 4; ++g) {
            const int o0 = 32 * ob + 8 * g + 4 * h;
            const int rb = 4 * g;
            if (o0 + 3 < NOSC) {               // pad only (ob=1,g=3,h=1): osc 60-63
                const float4 tv = *(const float4*)(theta_in + brow + o0);
                const float4 ov = *(const float4*)(omega + o0);
                th[ob][rb+0] = tv.x; th[ob][rb+1] = tv.y; th[ob][rb+2] = tv.z; th[ob][rb+3] = tv.w;
                omg[ob][rb+0] = ov.x; omg[ob][rb+1] = ov.y; omg[ob][rb+2] = ov.z; omg[ob][rb+3] = ov.w;
            } else {
#pragma unroll
                for (int m = 0; m < 4; ++m) { th[ob][rb+m] = 0.0f; omg[ob][rb+m] = 0.0f; }
            }
#pragma unroll
            for (int m = 0; m < 4; ++m)
                fast_sincos(th[ob][rb+m], &sn[ob][rb+m], &cn[ob][rb+m]);
        }
    }

    // wrap constants (boundary-exact, see R3 notes)
    const float PI_F = 3.14159274101257324f;
    const float C_HI = 6.28318548202514648f;    // f32(2pi)
    const float C_LO = -1.7484556e-7f;          // 2pi - C_HI (f64-accurate)

#pragma unroll 1
    for (int t = 0; t < STEPS; ++t) {
        floatx16 aS0, aS1, aC0, aC1;
        const floatx16 Z = (floatx16)0.0f;

#pragma unroll
        for (int kb = 0; kb < 4; ++kb) {
            // B source: state elems (obp, r0+j), j=0..7 -- IDENTITY packing.
            const int obp = kb >> 1;
            const int r0  = (kb & 1) * 8;

            float sl_[8], cl_[8];
#pragma unroll
            for (int s = 0; s < 8; ++s) {
                const unsigned us = fbits(sn[obp][r0+s]);
                sl_[s] = sn[obp][r0+s] - bitsf(us & 0xffff0000u);
                const unsigned uc = fbits(cn[obp][r0+s]);
                cl_[s] = cn[obp][r0+s] - bitsf(uc & 0xffff0000u);
            }
            union BU { unsigned u[4]; short8v v; };
            BU Bsh, Bsl, Bch, Bcl;
#pragma unroll
            for (int p = 0; p < 4; ++p) {
                Bsh.u[p] = pack_hi_pair(sn[obp][r0+2*p], sn[obp][r0+2*p+1]);
                Bsl.u[p] = pack_hi_pair(sl_[2*p], sl_[2*p+1]);
                Bch.u[p] = pack_hi_pair(cn[obp][r0+2*p], cn[obp][r0+2*p+1]);
                Bcl.u[p] = pack_hi_pair(cl_[2*p], cl_[2*p+1]);
            }

            // 12 MFMAs, product-major S/C interleave (same-acc distance 4).
            // Per-acc product order: H.BH, L.BH, H.BL -- unchanged.
            aS0 = mfma32(AH[0][kb], Bsh.v, (kb == 0) ? Z : aS0);
            aS1 = mfma32(AH[1][kb], Bsh.v, (kb == 0) ? Z : aS1);
            aC0 = mfma32(AH[0][kb], Bch.v, (kb == 0) ? Z : aC0);
            aC1 = mfma32(AH[1][kb], Bch.v, (kb == 0) ? Z : aC1);
            aS0 = mfma32(AL[0][kb], Bsh.v, aS0);
            aS1 = mfma32(AL[1][kb], Bsh.v, aS1);
            aC0 = mfma32(AL[0][kb], Bch.v, aC0);
            aC1 = mfma32(AL[1][kb], Bch.v, aC1);
            aS0 = mfma32(AH[0][kb], Bsl.v, aS0);
            aS1 = mfma32(AH[1][kb], Bsl.v, aS1);
            aC0 = mfma32(AH[0][kb], Bcl.v, aC0);
            aC1 = mfma32(AH[1][kb], Bcl.v, aC1);
        }

        // ---- update: ref-exact association + boundary-exact wrap
#pragma unroll
        for (int ob = 0; ob < 2; ++ob) {
            const floatx16 &aS = ob ? aS1 : aS0;
            const floatx16 &aC = ob ? aC1 : aC0;
#pragma unroll
            for (int r = 0; r < 16; ++r) {
                const float S = aS[r];
                const float C = aC[r];
                const float coup = cn[ob][r] * S - sn[ob][r] * C;  // approx path: fma ok
                float nth;
                {
#pragma clang fp contract(off)
                    const float t1 = scale * coup;       // np: scale*coupling_sum
                    const float t2 = omg[ob][r] + t1;    // np: omega + ...
                    const float t3 = eff_dt * t2;        // np: eff_dt * (...)
                    nth = th[ob][r] + t3;                // np: th + ...
                }
                float n = 0.0f;
                n = (nth >=  PI_F) ?  1.0f : n;
                n = (nth <= -PI_F) ? -1.0f : n;
                float y = fmaf(n, -C_HI, nth);
                y = fmaf(n, -C_LO, y);
                th[ob][r] = y;
                fast_sincos(y, &sn[ob][r], &cn[ob][r]);
            }
        }
    }

    // ---- epilogue: store wrapped theta (float4 per (ob,g), pad chunk skipped)
#pragma unroll
    for (int ob = 0; ob < 2; ++ob) {
#pragma unroll
        for (int g = 0; g < 4; ++g) {
            const int o0 = 32 * ob + 8 * g + 4 * h;
            const int rb = 4 * g;
            if (o0 + 3 < NOSC) {
                float4 tv;
                tv.x = th[ob][rb+0]; tv.y = th[ob][rb+1];
                tv.z = th[ob][rb+2]; tv.w = th[ob][rb+3];
                *(float4*)(theta_out + brow + o0) = tv;
            }
        }
    }

    // ---- coherence: batch = batch0 + c split across lane halves.
    // Pad elems (ob=1, regs 12-15, h=1) hold exactly (sn,cn)=(0,1) forever:
    // sum all 32 then subtract the 4 pad cosines at h==1.
    float pc = 0.0f, ps = 0.0f;
#pragma unroll
    for (int ob = 0; ob < 2; ++ob)
#pragma unroll
        for (int r = 0; r < 16; ++r) { pc += cn[ob][r]; ps += sn[ob][r]; }
    pc -= h ? 4.0f : 0.0f;
    pc += __shfl_xor(pc, 32);
    ps += __shfl_xor(ps, 32);
    if (h == 0) {
        const float cm = pc / 60.0f;
        const float sm = ps / 60.0f;
        coh_out[batch0 + c] = sqrtf(cm * cm + sm * sm);
    }
}

extern "C" void kernel_launch(void* const* d_in, const int* in_sizes, int n_in,
                              void* d_out, int out_size, void* d_ws, size_t ws_size,
                              hipStream_t stream) {
    const float* theta = (const float*)d_in[0];
    const float* Kmat  = (const float*)d_in[1];
    const float* omg   = (const float*)d_in[2];
    const float* kg    = (const float*)d_in[3];
    const float* cmod  = (const float*)d_in[4];
    const float* gate  = (const float*)d_in[5];
    const float* slow  = (const float*)d_in[6];
    const float* dsn   = (const float*)d_in[7];
    const float* relax = (const float*)d_in[8];
    float* out = (float*)d_out;

    kuramoto_kernel<<<dim3(B_TOTAL / 32), dim3(64), 0, stream>>>(
        theta, Kmat, omg, kg, cmod, gate, slow, dsn, relax,
        out, out + (size_t)B_TOTAL * NOSC);
}

// Round 10
// 119.893 us; speedup vs baseline: 1.0413x; 1.0094x over previous
//
#include <hip/hip_runtime.h>
#include <stdint.h>
#include <math.h>

// Kuramoto dynamics, B=65536 x N=60, 10 steps.
// R13: R12 + packed-f32 (VOP3P) element math + 3-op wrap select.
//   R12 post-mortem: native-sincos null -> __sincosf was already native;
//   VALUBusy is ~2x inflated (gfx94x 4-cyc formula on 2-cyc CDNA4 issue).
//   Across R4-R12 wall tracks TOTAL ISSUED INSTRUCTIONS (R6 worst, R10/R12
//   best); remaining lever = cut VALU count at fixed numerics.
//   Changes (all bitwise-neutral on the theta path):
//   - update/wrap/split arithmetic over float2 pairs -> v_pk_{fma,mul,add}_f32
//     (2 IEEE f32 ops/instr; per-component rounding == scalar; contract(off)
//     applies to vector ops).
//   - wrap select: n = (|nth| >= pi) ? copysign(1,nth) : 0  -- v_cmp(abs mod)
//     + v_bfi + v_cndmask = 3 ops vs 4. Same predicate boundary-exactness
//     (|x|>=pi <=> x>=pi or x<=-pi); n*C_HI / n*C_LO exact for n in {0,+-1}
//     so mul+add == fmaf(n,-C,x) bitwise.
//   ~672 -> ~480 VALU/step.
// Carried from R10/R12:
//   - exchange-free 32x32x16 MFMA: sigma-gathered A columns
//     (A slot(h,j) = Ke[m][16kb+(j&3)+8(j>>2)+4h]); B packing is the IDENTITY
//     on C/D state elems; zero cross-lane ops in the loop.
//   - 3-product split: KH.sH + KL.sH + KH.sL, kb order 0..3, 4-acc rotation.
//   - update: 4 separately-rounded f32 ops (#pragma clang fp contract(off))
//   - native sincos: r = x*(1/2pi); v_sin_f32/v_cos_f32 (|r| < 0.6).

#define B_TOTAL 65536
#define NOSC 60
#define STEPS 10

using short8v  = __attribute__((ext_vector_type(8))) short;
using floatx16 = __attribute__((ext_vector_type(16))) float;
using bf16x8   = __attribute__((ext_vector_type(8))) __bf16;
using float2v  = __attribute__((ext_vector_type(2))) float;

#if __has_builtin(__builtin_amdgcn_perm)
__device__ __forceinline__ unsigned int perm_b32(unsigned int s0, unsigned int s1, unsigned int sel) {
    return __builtin_amdgcn_perm(s0, s1, sel);
}
#else
__device__ __forceinline__ unsigned int perm_b32(unsigned int s0, unsigned int s1, unsigned int sel) {
    unsigned long long pool = ((unsigned long long)s0 << 32) | s1;
    unsigned int r = 0;
#pragma unroll
    for (int b = 0; b < 4; ++b) {
        unsigned int s = (sel >> (8 * b)) & 0xff;
        r |= ((unsigned int)((pool >> (8 * s)) & 0xff)) << (8 * b);
    }
    return r;
}
#endif

__device__ __forceinline__ unsigned int fbits(float x)        { return __builtin_bit_cast(unsigned int, x); }
__device__ __forceinline__ float        bitsf(unsigned int u) { return __builtin_bit_cast(float, u); }

// 32x32x16 bf16 MFMA. Builtin if present (v8bf16 operands), else inline asm.
__device__ __forceinline__ floatx16 mfma32(short8v a, short8v b, floatx16 c) {
#if __has_builtin(__builtin_amdgcn_mfma_f32_32x32x16_bf16)
    return __builtin_amdgcn_mfma_f32_32x32x16_bf16(
        __builtin_bit_cast(bf16x8, a), __builtin_bit_cast(bf16x8, b), c, 0, 0, 0);
#else
    asm("v_mfma_f32_32x32x16_bf16 %0, %1, %2, %0" : "+v"(c) : "v"(a), "v"(b));
    return c;
#endif
}

// pack bf16-hi(a) into low half, bf16-hi(b) into high half of one b32
__device__ __forceinline__ unsigned int pack_hi_pair(float a, float b) {
    return perm_b32(fbits(b), fbits(a), 0x07060302u);
}

__global__ __launch_bounds__(64)
void kuramoto_kernel(const float* __restrict__ theta_in,
                     const float* __restrict__ Kmat,
                     const float* __restrict__ omega,
                     const float* __restrict__ p_kglobal,
                     const float* __restrict__ p_cmod,
                     const float* __restrict__ p_gate,
                     const float* __restrict__ p_slow,
                     const float* __restrict__ p_dsneg,
                     const float* __restrict__ p_relax,
                     float* __restrict__ theta_out,
                     float* __restrict__ coh_out)
{
    const int lane = threadIdx.x & 63;
    const int c    = lane & 31;   // batch within tile
    const int h    = lane >> 5;   // lane half

    const float kglobal = p_kglobal[0];
    const float cmod    = p_cmod[0];
    const float gate    = p_gate[0];
    const float slow    = p_slow[0];
    const float dsneg   = p_dsneg[0];
    const float relax   = p_relax[0];

    float eff_dt, scale;
    {
#pragma clang fp contract(off)
        const float a     = slow * relax;
        const float b     = 1.0f + a;
        const float crit  = 1.0f / b;
        eff_dt            = 0.1f * crit;
        const float boost = 1.0f + gate * dsneg;
        scale             = (kglobal * boost) / 60.0f;
    }

    const int batch0 = blockIdx.x * 32;
    const int brow   = (batch0 + c) * NOSC;

    // ---- A operand (loop-invariant): Ke = K*cmod, hi/lo trunc split, with
    // sigma-gathered k columns: A slot (h,j) = Ke[m][16*kb + (j&3) + 8*(j>>2) + 4*h]
    // matching the natural (identity) B packing of C/D state elems.
    short8v AH[2][4], AL[2][4];
#pragma unroll
    for (int ob = 0; ob < 2; ++ob) {
        const int m = 32 * ob + c;
        const bool okm = (m < NOSC);          // zero rows >= 60 -> acc rows 60..63 = 0
#pragma unroll
        for (int kb = 0; kb < 4; ++kb) {
            const int base = 16 * kb + 4 * h;
            float kv[8];
            if (okm && (base + 11) < NOSC) {
                const float4 a = *(const float4*)(Kmat + m * NOSC + base);
                const float4 b = *(const float4*)(Kmat + m * NOSC + base + 8);
                kv[0]=a.x; kv[1]=a.y; kv[2]=a.z; kv[3]=a.w;
                kv[4]=b.x; kv[5]=b.y; kv[6]=b.z; kv[7]=b.w;
            } else {
#pragma unroll
                for (int j = 0; j < 8; ++j) {
                    const int col = base + (j & 3) + 8 * (j >> 2);
                    kv[j] = (okm && col < NOSC) ? Kmat[m * NOSC + col] : 0.0f;
                }
            }
            short8v hh, ll;
#pragma unroll
            for (int j = 0; j < 8; ++j) {
                const float v = kv[j] * cmod;
                const unsigned int hb = fbits(v) & 0xffff0000u;
                const float rlo = v - bitsf(hb);
                hh[j] = (short)(hb >> 16);
                ll[j] = (short)(fbits(rlo) >> 16);
            }
            AH[ob][kb] = hh;
            AL[ob][kb] = ll;
        }
    }

    // ---- state in 32x32 C/D layout as float2 PAIRS: pair (ob, p) holds
    //   elems r = 2p, 2p+1  ->  osc o = 32*ob + (r&3) + 8*(r>>2) + 4*h.
    float2v th2[2][8], sn2[2][8], cn2[2][8], om2[2][8];
#pragma unroll
    for (int ob = 0; ob < 2; ++ob) {
#pragma unroll
        for (int g = 0; g < 4; ++g) {
            const int o0 = 32 * ob + 8 * g + 4 * h;
            const int p0 = 2 * g;
            if (o0 + 3 < NOSC) {               // pad only (ob=1,g=3,h=1): osc 60-63
                const float4 tv = *(const float4*)(theta_in + brow + o0);
                const float4 ov = *(const float4*)(omega + o0);
                th2[ob][p0]   = float2v{tv.x, tv.y};
                th2[ob][p0+1] = float2v{tv.z, tv.w};
                om2[ob][p0]   = float2v{ov.x, ov.y};
                om2[ob][p0+1] = float2v{ov.z, ov.w};
            } else {
                th2[ob][p0] = (float2v)0.0f; th2[ob][p0+1] = (float2v)0.0f;
                om2[ob][p0] = (float2v)0.0f; om2[ob][p0+1] = (float2v)0.0f;
            }
#pragma unroll
            for (int q = 0; q < 2; ++q) {
                const float2v r2 = th2[ob][p0+q] * 0.15915494309189535f;
                float s0, c0, s1, c1;
                asm("v_sin_f32 %0, %1" : "=v"(s0) : "v"(r2[0]));
                asm("v_cos_f32 %0, %1" : "=v"(c0) : "v"(r2[0]));
                asm("v_sin_f32 %0, %1" : "=v"(s1) : "v"(r2[1]));
                asm("v_cos_f32 %0, %1" : "=v"(c1) : "v"(r2[1]));
                sn2[ob][p0+q] = float2v{s0, s1};
                cn2[ob][p0+q] = float2v{c0, c1};
            }
        }
    }

    // wrap constants (boundary-exact, see R3 notes)
    const float PI_F = 3.14159274101257324f;
    const float C_HI = 6.28318548202514648f;    // f32(2pi)
    const float C_LO = -1.7484556e-7f;          // 2pi - C_HI (f64-accurate)
    const float2v scale2 = (float2v)scale;
    const float2v effdt2 = (float2v)eff_dt;

#pragma unroll 1
    for (int t = 0; t < STEPS; ++t) {
        floatx16 aS0, aS1, aC0, aC1;
        const floatx16 Z = (floatx16)0.0f;

#pragma unroll
        for (int kb = 0; kb < 4; ++kb) {
            // B source: state pairs (obp, p0..p0+3) -- IDENTITY packing.
            const int obp = kb >> 1;
            const int p0  = (kb & 1) * 4;

            union BU { unsigned u[4]; short8v v; };
            BU Bsh, Bsl, Bch, Bcl;
#pragma unroll
            for (int p = 0; p < 4; ++p) {
                const float2v s2 = sn2[obp][p0+p];
                const float2v c2 = cn2[obp][p0+p];
                const float2v sh2 = float2v{bitsf(fbits(s2[0]) & 0xffff0000u),
                                            bitsf(fbits(s2[1]) & 0xffff0000u)};
                const float2v ch2 = float2v{bitsf(fbits(c2[0]) & 0xffff0000u),
                                            bitsf(fbits(c2[1]) & 0xffff0000u)};
                const float2v sl2 = s2 - sh2;   // v_pk_add (neg mod)
                const float2v cl2 = c2 - ch2;
                Bsh.u[p] = pack_hi_pair(s2[0], s2[1]);
                Bsl.u[p] = pack_hi_pair(sl2[0], sl2[1]);
                Bch.u[p] = pack_hi_pair(c2[0], c2[1]);
                Bcl.u[p] = pack_hi_pair(cl2[0], cl2[1]);
            }

            // 12 MFMAs, product-major S/C interleave (same-acc distance 4).
            // Per-acc product order: H.BH, L.BH, H.BL -- unchanged.
            aS0 = mfma32(AH[0][kb], Bsh.v, (kb == 0) ? Z : aS0);
            aS1 = mfma32(AH[1][kb], Bsh.v, (kb == 0) ? Z : aS1);
            aC0 = mfma32(AH[0][kb], Bch.v, (kb == 0) ? Z : aC0);
            aC1 = mfma32(AH[1][kb], Bch.v, (kb == 0) ? Z : aC1);
            aS0 = mfma32(AL[0][kb], Bsh.v, aS0);
            aS1 = mfma32(AL[1][kb], Bsh.v, aS1);
            aC0 = mfma32(AL[0][kb], Bch.v, aC0);
            aC1 = mfma32(AL[1][kb], Bch.v, aC1);
            aS0 = mfma32(AH[0][kb], Bsl.v, aS0);
            aS1 = mfma32(AH[1][kb], Bsl.v, aS1);
            aC0 = mfma32(AH[0][kb], Bcl.v, aC0);
            aC1 = mfma32(AH[1][kb], Bcl.v, aC1);
        }

        // ---- update (packed pairs): ref-exact association + boundary-exact wrap
#pragma unroll
        for (int ob = 0; ob < 2; ++ob) {
            const floatx16 &aS = ob ? aS1 : aS0;
            const floatx16 &aC = ob ? aC1 : aC0;
#pragma unroll
            for (int p = 0; p < 8; ++p) {
                const float2v S = float2v{aS[2*p], aS[2*p+1]};
                const float2v C = float2v{aC[2*p], aC[2*p+1]};
                const float2v coup = cn2[ob][p] * S - sn2[ob][p] * C;  // approx path: fma ok
                float2v nth;
                {
#pragma clang fp contract(off)
                    const float2v t1 = scale2 * coup;     // np: scale*coupling_sum
                    const float2v t2 = om2[ob][p] + t1;   // np: omega + ...
                    const float2v t3 = effdt2 * t2;       // np: eff_dt * (...)
                    nth = th2[ob][p] + t3;                // np: th + ...
                }
                // 3-op select: n = (|nth|>=pi) ? copysign(1,nth) : 0
                float2v n2;
                n2[0] = (__builtin_fabsf(nth[0]) >= PI_F) ? __builtin_copysignf(1.0f, nth[0]) : 0.0f;
                n2[1] = (__builtin_fabsf(nth[1]) >= PI_F) ? __builtin_copysignf(1.0f, nth[1]) : 0.0f;
                // n*C exact (n in {0,+-1}) -> mul+add bitwise == fmaf(n,-C,x)
                float2v y = nth - n2 * C_HI;
                y = y - n2 * C_LO;
                th2[ob][p] = y;
                const float2v r2 = y * 0.15915494309189535f;
                float s0v, c0v, s1v, c1v;
                asm("v_sin_f32 %0, %1" : "=v"(s0v) : "v"(r2[0]));
                asm("v_cos_f32 %0, %1" : "=v"(c0v) : "v"(r2[0]));
                asm("v_sin_f32 %0, %1" : "=v"(s1v) : "v"(r2[1]));
                asm("v_cos_f32 %0, %1" : "=v"(c1v) : "v"(r2[1]));
                sn2[ob][p] = float2v{s0v, s1v};
                cn2[ob][p] = float2v{c0v, c1v};
            }
        }
    }

    // ---- epilogue: store wrapped theta (float4 per (ob,g), pad chunk skipped)
#pragma unroll
    for (int ob = 0; ob < 2; ++ob) {
#pragma unroll
        for (int g = 0; g < 4; ++g) {
            const int o0 = 32 * ob + 8 * g + 4 * h;
            const int p0 = 2 * g;
            if (o0 + 3 < NOSC) {
                float4 tv;
                tv.x = th2[ob][p0][0];   tv.y = th2[ob][p0][1];
                tv.z = th2[ob][p0+1][0]; tv.w = th2[ob][p0+1][1];
                *(float4*)(theta_out + brow + o0) = tv;
            }
        }
    }

    // ---- coherence: batch = batch0 + c split across lane halves.
    // Pad elems (ob=1, pairs 6-7, h=1) hold exactly (sn,cn)=(0,1) forever:
    // sum all 32 then subtract the 4 pad cosines at h==1.
    float2v pc2 = (float2v)0.0f, ps2 = (float2v)0.0f;
#pragma unroll
    for (int ob = 0; ob < 2; ++ob)
#pragma unroll
        for (int p = 0; p < 8; ++p) { pc2 += cn2[ob][p]; ps2 += sn2[ob][p]; }
    float pc = pc2[0] + pc2[1];
    float ps = ps2[0] + ps2[1];
    pc -= h ? 4.0f : 0.0f;
    pc += __shfl_xor(pc, 32);
    ps += __shfl_xor(ps, 32);
    if (h == 0) {
        const float cm = pc / 60.0f;
        const float sm = ps / 60.0f;
        coh_out[batch0 + c] = sqrtf(cm * cm + sm * sm);
    }
}

extern "C" void kernel_launch(void* const* d_in, const int* in_sizes, int n_in,
                              void* d_out, int out_size, void* d_ws, size_t ws_size,
                              hipStream_t stream) {
    const float* theta = (const float*)d_in[0];
    const float* Kmat  = (const float*)d_in[1];
    const float* omg   = (const float*)d_in[2];
    const float* kg    = (const float*)d_in[3];
    const float* cmod  = (const float*)d_in[4];
    const float* gate  = (const float*)d_in[5];
    const float* slow  = (const float*)d_in[6];
    const float* dsn   = (const float*)d_in[7];
    const float* relax = (const float*)d_in[8];
    float* out = (float*)d_out;

    kuramoto_kernel<<<dim3(B_TOTAL / 32), dim3(64), 0, stream>>>(
        theta, Kmat, omg, kg, cmod, gate, slow, dsn, relax,
        out, out + (size_t)B_TOTAL * NOSC);
}